// Round 9
// baseline (245.249 us; speedup 1.0000x reference)
//
#include <hip/hip_runtime.h>
#include <math.h>

#define H_IN   136
#define W_IN   200
#define HWP    (H_IN * W_IN)       // 27200
#define OH     272
#define OW     400
#define RB     8                   // low-res rows per strip (17 strips)
#define NSTRIP 17
#define LROWS  (RB + 1)            // +1 halo row above
#define CH     8
#define CIN    8
#define NPARAM 169
#define NEG_LOG2E (-1.4426950408889634f)
#define P1U    (LROWS * (W_IN / 4))   // 450 phase-1 units (4 px each)
#define P2U    (RB * (W_IN / 4))      // 400 phase-2 units (16 px each)

// Param layout per instance (169 floats):
//  [0..79] w0[8][10] | [80..143] w1[8][8] | [144..151] w2[8]
//  [152..159] b0[8]  | [160..167] b1[8]   | [168] b2

// R9 change (isolated): phase 1 = 4 px/thread (was 8) -> ~85 live VGPR
// (was ~160 at the 168 cap) -> __launch_bounds__(256,5): 5 waves/SIMD
// instead of 3. Occupancy was the theory for the 2.2x gap to the
// issue+store floor. Everything else identical to R8.
__global__ __launch_bounds__(256, 5) void mask_head_fused(
    const float* __restrict__ mask_feats,   // (N, 8, H, W)
    const float* __restrict__ params,       // (n_inst, 169)
    const float* __restrict__ locations,    // (n_inst, 2)
    const int*   __restrict__ im_inds,      // (n_inst,)
    const int*   __restrict__ fpn_levels,   // (n_inst,)
    const float* __restrict__ soi_tab,      // (5,)
    float* __restrict__ out)                // (n_inst, 272, 400)
{
    __shared__ float sW[NPARAM];
    __shared__ float T[LROWS][W_IN];        // t = -log2e * logit, rows r0-1..r0+7

    const int inst = blockIdx.y;
    const int r0   = blockIdx.x * RB;
    const int tid  = threadIdx.x;

    const float* P = params + inst * NPARAM;
    if (tid < NPARAM) sW[tid] = P[tid];

    const float loc_x   = locations[2 * inst];
    const float loc_y   = locations[2 * inst + 1];
    const float inv_soi = 1.0f / soi_tab[fpn_levels[inst]];
    const float* F = mask_feats + (size_t)im_inds[inst] * (CIN * HWP);
    __syncthreads();

    // ---- Phase 1: 450 units of 4 px (9 rows x 50 units/row), 2 iterations ----
    #pragma unroll 1
    for (int it = 0; it < 2; ++it) {
        const int s = tid + it * 256;
        if (s < P1U) {
            const int k = s / 50;
            const int c = (s - k * 50) * 4;
            const int r = min(max(r0 - 1 + k, 0), H_IN - 1);

            float4 f[CIN];
            #pragma unroll
            for (int ch = 0; ch < CIN; ++ch)
                f[ch] = *(const float4*)(F + ch * HWP + r * W_IN + c);

            const float ry = (loc_y - (float)(r * 8 + 4)) * inv_soi;
            const float dx = -8.0f * inv_soi;
            float rx[4];
            rx[0] = (loc_x - (float)(c * 8 + 4)) * inv_soi;
            rx[1] = rx[0] + dx; rx[2] = rx[1] + dx; rx[3] = rx[2] + dx;

            float h0[CH][4];
            #pragma unroll
            for (int o = 0; o < CH; ++o) {
                const float b  = sW[152 + o];
                const float wx = sW[o * 10 + 0];
                const float wy = sW[o * 10 + 1];
                float a0 = fmaf(wx, rx[0], fmaf(wy, ry, b));
                float a1 = fmaf(wx, rx[1], fmaf(wy, ry, b));
                float a2 = fmaf(wx, rx[2], fmaf(wy, ry, b));
                float a3 = fmaf(wx, rx[3], fmaf(wy, ry, b));
                #pragma unroll
                for (int i = 0; i < CIN; ++i) {
                    const float w = sW[o * 10 + 2 + i];
                    a0 = fmaf(w, f[i].x, a0); a1 = fmaf(w, f[i].y, a1);
                    a2 = fmaf(w, f[i].z, a2); a3 = fmaf(w, f[i].w, a3);
                }
                h0[o][0] = fmaxf(a0, 0.0f); h0[o][1] = fmaxf(a1, 0.0f);
                h0[o][2] = fmaxf(a2, 0.0f); h0[o][3] = fmaxf(a3, 0.0f);
            }

            float h1[CH][4];
            #pragma unroll
            for (int o = 0; o < CH; ++o) {
                const float b = sW[160 + o];
                float a0 = b, a1 = b, a2 = b, a3 = b;
                #pragma unroll
                for (int i = 0; i < CH; ++i) {
                    const float w = sW[80 + o * CH + i];
                    a0 = fmaf(w, h0[i][0], a0); a1 = fmaf(w, h0[i][1], a1);
                    a2 = fmaf(w, h0[i][2], a2); a3 = fmaf(w, h0[i][3], a3);
                }
                h1[o][0] = fmaxf(a0, 0.0f); h1[o][1] = fmaxf(a1, 0.0f);
                h1[o][2] = fmaxf(a2, 0.0f); h1[o][3] = fmaxf(a3, 0.0f);
            }

            const float b2 = NEG_LOG2E * sW[168];
            float t0 = b2, t1 = b2, t2 = b2, t3 = b2;
            #pragma unroll
            for (int i = 0; i < CH; ++i) {
                const float w = NEG_LOG2E * sW[144 + i];
                t0 = fmaf(w, h1[i][0], t0); t1 = fmaf(w, h1[i][1], t1);
                t2 = fmaf(w, h1[i][2], t2); t3 = fmaf(w, h1[i][3], t3);
            }
            *(float4*)&T[k][c] = make_float4(t0, t1, t2, t3);
        }
    }
    __syncthreads();

    // ---- Phase 2: 400 units of 16 px (8 wide x 2 output rows) ----
    // Output rows (2rp, 2rp+1) need low-res rows rp-1 (slot rpl) and rp
    // (slot rpl+1); strip-0 boundary handled by phase 1's row clamp.
    float* O = out + (size_t)inst * (OH * OW);
    #pragma unroll
    for (int it = 0; it < 2; ++it) {
        const int s = tid + 256 * it;
        if (s < P2U) {
            const int rpl = s / (W_IN / 4);         // 0..7
            const int t   = s - rpl * (W_IN / 4);   // 0..49
            const int cm  = 4 * t;
            const int cl  = max(cm - 1, 0);

            const float4 mR = *(const float4*)&T[rpl + 1][cm];
            const float4 mQ = *(const float4*)&T[rpl][cm];
            const float  AR = T[rpl + 1][cl];       // == mR.x when t==0
            const float  AQ = T[rpl][cl];

            const float Aa = 0.5f * (AR + AQ);
            const float Ba = 0.5f * (mR.x + mQ.x);
            const float Ca = 0.5f * (mR.y + mQ.y);
            const float Da = 0.5f * (mR.z + mQ.z);
            const float Ea = 0.5f * (mR.w + mQ.w);

            float4 s0, s1, s2, s3;
            s0.x = __builtin_amdgcn_rcpf(1.0f + __builtin_amdgcn_exp2f(0.5f * (Aa + Ba)));
            s0.y = __builtin_amdgcn_rcpf(1.0f + __builtin_amdgcn_exp2f(Ba));
            s0.z = __builtin_amdgcn_rcpf(1.0f + __builtin_amdgcn_exp2f(0.5f * (Ba + Ca)));
            s0.w = __builtin_amdgcn_rcpf(1.0f + __builtin_amdgcn_exp2f(Ca));
            s1.x = __builtin_amdgcn_rcpf(1.0f + __builtin_amdgcn_exp2f(0.5f * (Ca + Da)));
            s1.y = __builtin_amdgcn_rcpf(1.0f + __builtin_amdgcn_exp2f(Da));
            s1.z = __builtin_amdgcn_rcpf(1.0f + __builtin_amdgcn_exp2f(0.5f * (Da + Ea)));
            s1.w = __builtin_amdgcn_rcpf(1.0f + __builtin_amdgcn_exp2f(Ea));

            s2.x = __builtin_amdgcn_rcpf(1.0f + __builtin_amdgcn_exp2f(0.5f * (AR + mR.x)));
            s2.y = __builtin_amdgcn_rcpf(1.0f + __builtin_amdgcn_exp2f(mR.x));
            s2.z = __builtin_amdgcn_rcpf(1.0f + __builtin_amdgcn_exp2f(0.5f * (mR.x + mR.y)));
            s2.w = __builtin_amdgcn_rcpf(1.0f + __builtin_amdgcn_exp2f(mR.y));
            s3.x = __builtin_amdgcn_rcpf(1.0f + __builtin_amdgcn_exp2f(0.5f * (mR.y + mR.z)));
            s3.y = __builtin_amdgcn_rcpf(1.0f + __builtin_amdgcn_exp2f(mR.z));
            s3.z = __builtin_amdgcn_rcpf(1.0f + __builtin_amdgcn_exp2f(0.5f * (mR.z + mR.w)));
            s3.w = __builtin_amdgcn_rcpf(1.0f + __builtin_amdgcn_exp2f(mR.w));

            float* O0 = O + (size_t)(2 * (r0 + rpl)) * OW + 8 * t;
            *(float4*)(O0)          = s0;
            *(float4*)(O0 + 4)      = s1;
            *(float4*)(O0 + OW)     = s2;
            *(float4*)(O0 + OW + 4) = s3;
        }
    }
}

extern "C" void kernel_launch(void* const* d_in, const int* in_sizes, int n_in,
                              void* d_out, int out_size, void* d_ws, size_t ws_size,
                              hipStream_t stream) {
    const float* mask_feats = (const float*)d_in[0];
    const float* params     = (const float*)d_in[1];
    const float* locations  = (const float*)d_in[2];
    const int*   im_inds    = (const int*)d_in[3];
    const int*   fpn_levels = (const int*)d_in[4];
    const float* soi_tab    = (const float*)d_in[5];

    const int n_inst = in_sizes[1] / NPARAM;   // 128
    dim3 grid(NSTRIP, n_inst);                 // (17, 128)
    mask_head_fused<<<grid, 256, 0, stream>>>(
        mask_feats, params, locations, im_inds, fpn_levels, soi_tab, (float*)d_out);
}

// Round 10
// 198.895 us; speedup vs baseline: 1.2331x; 1.2331x over previous
//
#include <hip/hip_runtime.h>
#include <math.h>

#define H_IN   136
#define W_IN   200
#define HWP    (H_IN * W_IN)       // 27200
#define OH     272
#define OW     400
#define RB     8                   // low-res rows per strip (17 strips)
#define NSTRIP 17
#define LROWS  (RB + 1)            // +1 halo row above
#define CH     8
#define CIN    8
#define NPARAM 169
#define NEG_LOG2E (-1.4426950408889634f)
#define P1U    (LROWS * (W_IN / 4))   // 450 phase-1 units (4 px each)
#define P2U    (RB * (W_IN / 4))      // 400 phase-2 units (16 px each)

// Param layout per instance (169 floats):
//  [0..79] w0[8][10] | [80..143] w1[8][8] | [144..151] w2[8]
//  [152..159] b0[8]  | [160..167] b1[8]   | [168] b2

// R10: same 4px/thread structure as R9 but __launch_bounds__(256,4)
// (128-VGPR cap). R9's (256,5)=96 cap SPILLED the f[] array to scratch
// (VGPR_Count=48, FETCH_SIZE=467MB, 245us). Live-range count says ~80
// peak -> fits 128 with headroom; target 4 waves/SIMD vs R8's 3.
__global__ __launch_bounds__(256, 4) void mask_head_fused(
    const float* __restrict__ mask_feats,   // (N, 8, H, W)
    const float* __restrict__ params,       // (n_inst, 169)
    const float* __restrict__ locations,    // (n_inst, 2)
    const int*   __restrict__ im_inds,      // (n_inst,)
    const int*   __restrict__ fpn_levels,   // (n_inst,)
    const float* __restrict__ soi_tab,      // (5,)
    float* __restrict__ out)                // (n_inst, 272, 400)
{
    __shared__ float sW[NPARAM];
    __shared__ float T[LROWS][W_IN];        // t = -log2e * logit, rows r0-1..r0+7

    const int inst = blockIdx.y;
    const int r0   = blockIdx.x * RB;
    const int tid  = threadIdx.x;

    const float* P = params + inst * NPARAM;
    if (tid < NPARAM) sW[tid] = P[tid];

    const float loc_x   = locations[2 * inst];
    const float loc_y   = locations[2 * inst + 1];
    const float inv_soi = 1.0f / soi_tab[fpn_levels[inst]];
    const float* F = mask_feats + (size_t)im_inds[inst] * (CIN * HWP);
    __syncthreads();

    // ---- Phase 1: 450 units of 4 px (9 rows x 50 units/row), 2 iterations ----
    #pragma unroll 1
    for (int it = 0; it < 2; ++it) {
        const int s = tid + it * 256;
        if (s < P1U) {
            const int k = s / 50;
            const int c = (s - k * 50) * 4;
            const int r = min(max(r0 - 1 + k, 0), H_IN - 1);

            float4 f[CIN];
            #pragma unroll
            for (int ch = 0; ch < CIN; ++ch)
                f[ch] = *(const float4*)(F + ch * HWP + r * W_IN + c);

            const float ry = (loc_y - (float)(r * 8 + 4)) * inv_soi;
            const float dx = -8.0f * inv_soi;
            float rx[4];
            rx[0] = (loc_x - (float)(c * 8 + 4)) * inv_soi;
            rx[1] = rx[0] + dx; rx[2] = rx[1] + dx; rx[3] = rx[2] + dx;

            float h0[CH][4];
            #pragma unroll
            for (int o = 0; o < CH; ++o) {
                const float b  = sW[152 + o];
                const float wx = sW[o * 10 + 0];
                const float wy = sW[o * 10 + 1];
                float a0 = fmaf(wx, rx[0], fmaf(wy, ry, b));
                float a1 = fmaf(wx, rx[1], fmaf(wy, ry, b));
                float a2 = fmaf(wx, rx[2], fmaf(wy, ry, b));
                float a3 = fmaf(wx, rx[3], fmaf(wy, ry, b));
                #pragma unroll
                for (int i = 0; i < CIN; ++i) {
                    const float w = sW[o * 10 + 2 + i];
                    a0 = fmaf(w, f[i].x, a0); a1 = fmaf(w, f[i].y, a1);
                    a2 = fmaf(w, f[i].z, a2); a3 = fmaf(w, f[i].w, a3);
                }
                h0[o][0] = fmaxf(a0, 0.0f); h0[o][1] = fmaxf(a1, 0.0f);
                h0[o][2] = fmaxf(a2, 0.0f); h0[o][3] = fmaxf(a3, 0.0f);
            }

            float h1[CH][4];
            #pragma unroll
            for (int o = 0; o < CH; ++o) {
                const float b = sW[160 + o];
                float a0 = b, a1 = b, a2 = b, a3 = b;
                #pragma unroll
                for (int i = 0; i < CH; ++i) {
                    const float w = sW[80 + o * CH + i];
                    a0 = fmaf(w, h0[i][0], a0); a1 = fmaf(w, h0[i][1], a1);
                    a2 = fmaf(w, h0[i][2], a2); a3 = fmaf(w, h0[i][3], a3);
                }
                h1[o][0] = fmaxf(a0, 0.0f); h1[o][1] = fmaxf(a1, 0.0f);
                h1[o][2] = fmaxf(a2, 0.0f); h1[o][3] = fmaxf(a3, 0.0f);
            }

            const float b2 = NEG_LOG2E * sW[168];
            float t0 = b2, t1 = b2, t2 = b2, t3 = b2;
            #pragma unroll
            for (int i = 0; i < CH; ++i) {
                const float w = NEG_LOG2E * sW[144 + i];
                t0 = fmaf(w, h1[i][0], t0); t1 = fmaf(w, h1[i][1], t1);
                t2 = fmaf(w, h1[i][2], t2); t3 = fmaf(w, h1[i][3], t3);
            }
            *(float4*)&T[k][c] = make_float4(t0, t1, t2, t3);
        }
    }
    __syncthreads();

    // ---- Phase 2: 400 units of 16 px (8 wide x 2 output rows) ----
    // Output rows (2rp, 2rp+1) need low-res rows rp-1 (slot rpl) and rp
    // (slot rpl+1); strip-0 boundary handled by phase 1's row clamp.
    float* O = out + (size_t)inst * (OH * OW);
    #pragma unroll
    for (int it = 0; it < 2; ++it) {
        const int s = tid + 256 * it;
        if (s < P2U) {
            const int rpl = s / (W_IN / 4);         // 0..7
            const int t   = s - rpl * (W_IN / 4);   // 0..49
            const int cm  = 4 * t;
            const int cl  = max(cm - 1, 0);

            const float4 mR = *(const float4*)&T[rpl + 1][cm];
            const float4 mQ = *(const float4*)&T[rpl][cm];
            const float  AR = T[rpl + 1][cl];       // == mR.x when t==0
            const float  AQ = T[rpl][cl];

            const float Aa = 0.5f * (AR + AQ);
            const float Ba = 0.5f * (mR.x + mQ.x);
            const float Ca = 0.5f * (mR.y + mQ.y);
            const float Da = 0.5f * (mR.z + mQ.z);
            const float Ea = 0.5f * (mR.w + mQ.w);

            float4 s0, s1, s2, s3;
            s0.x = __builtin_amdgcn_rcpf(1.0f + __builtin_amdgcn_exp2f(0.5f * (Aa + Ba)));
            s0.y = __builtin_amdgcn_rcpf(1.0f + __builtin_amdgcn_exp2f(Ba));
            s0.z = __builtin_amdgcn_rcpf(1.0f + __builtin_amdgcn_exp2f(0.5f * (Ba + Ca)));
            s0.w = __builtin_amdgcn_rcpf(1.0f + __builtin_amdgcn_exp2f(Ca));
            s1.x = __builtin_amdgcn_rcpf(1.0f + __builtin_amdgcn_exp2f(0.5f * (Ca + Da)));
            s1.y = __builtin_amdgcn_rcpf(1.0f + __builtin_amdgcn_exp2f(Da));
            s1.z = __builtin_amdgcn_rcpf(1.0f + __builtin_amdgcn_exp2f(0.5f * (Da + Ea)));
            s1.w = __builtin_amdgcn_rcpf(1.0f + __builtin_amdgcn_exp2f(Ea));

            s2.x = __builtin_amdgcn_rcpf(1.0f + __builtin_amdgcn_exp2f(0.5f * (AR + mR.x)));
            s2.y = __builtin_amdgcn_rcpf(1.0f + __builtin_amdgcn_exp2f(mR.x));
            s2.z = __builtin_amdgcn_rcpf(1.0f + __builtin_amdgcn_exp2f(0.5f * (mR.x + mR.y)));
            s2.w = __builtin_amdgcn_rcpf(1.0f + __builtin_amdgcn_exp2f(mR.y));
            s3.x = __builtin_amdgcn_rcpf(1.0f + __builtin_amdgcn_exp2f(0.5f * (mR.y + mR.z)));
            s3.y = __builtin_amdgcn_rcpf(1.0f + __builtin_amdgcn_exp2f(mR.z));
            s3.z = __builtin_amdgcn_rcpf(1.0f + __builtin_amdgcn_exp2f(0.5f * (mR.z + mR.w)));
            s3.w = __builtin_amdgcn_rcpf(1.0f + __builtin_amdgcn_exp2f(mR.w));

            float* O0 = O + (size_t)(2 * (r0 + rpl)) * OW + 8 * t;
            *(float4*)(O0)          = s0;
            *(float4*)(O0 + 4)      = s1;
            *(float4*)(O0 + OW)     = s2;
            *(float4*)(O0 + OW + 4) = s3;
        }
    }
}

extern "C" void kernel_launch(void* const* d_in, const int* in_sizes, int n_in,
                              void* d_out, int out_size, void* d_ws, size_t ws_size,
                              hipStream_t stream) {
    const float* mask_feats = (const float*)d_in[0];
    const float* params     = (const float*)d_in[1];
    const float* locations  = (const float*)d_in[2];
    const int*   im_inds    = (const int*)d_in[3];
    const int*   fpn_levels = (const int*)d_in[4];
    const float* soi_tab    = (const float*)d_in[5];

    const int n_inst = in_sizes[1] / NPARAM;   // 128
    dim3 grid(NSTRIP, n_inst);                 // (17, 128)
    mask_head_fused<<<grid, 256, 0, stream>>>(
        mask_feats, params, locations, im_inds, fpn_levels, soi_tab, (float*)d_out);
}

// Round 11
// 29.174 us; speedup vs baseline: 8.4066x; 6.8177x over previous
//
#include <hip/hip_runtime.h>
#include <math.h>

#define H_IN   136
#define W_IN   200
#define HWP    (H_IN * W_IN)       // 27200
#define OH     272
#define OW     400
#define RB     8                   // low-res rows per strip (17 strips)
#define NSTRIP 17
#define LROWS  (RB + 1)            // +1 halo row above
#define CH     8
#define CIN    8
#define NPARAM 169
#define NEG_LOG2E (-1.4426950408889634f)

// Param layout per instance (169 floats):
//  [0..79] w0[8][10] | [80..143] w1[8][8] | [144..151] w2[8]
//  [152..159] b0[8]  | [160..167] b1[8]   | [168] b2

// R11: revert to R8's proven structure/cap ((256,3); 8px pressure fit, so 4px
// strictly safe). ONE change: split the strip into two half-tiles and
// interleave P2a with P1b (disjoint T rows share a barrier epoch) so store
// bursts double in frequency / halve in length -> compute fills the store
// pipe's former dead windows.

__device__ __forceinline__ float4 mlp4(
    const float* __restrict__ F, const float* sW,
    float loc_x, float loc_y, float inv_soi, int r, int c)
{
    float4 f[CIN];
    #pragma unroll
    for (int ch = 0; ch < CIN; ++ch)
        f[ch] = *(const float4*)(F + ch * HWP + r * W_IN + c);

    const float ry = (loc_y - (float)(r * 8 + 4)) * inv_soi;
    const float dx = -8.0f * inv_soi;
    float rx0 = (loc_x - (float)(c * 8 + 4)) * inv_soi;
    float rx1 = rx0 + dx, rx2 = rx1 + dx, rx3 = rx2 + dx;

    float h0[CH][4];
    #pragma unroll
    for (int o = 0; o < CH; ++o) {
        const float b  = sW[152 + o];
        const float wx = sW[o * 10 + 0];
        const float wy = sW[o * 10 + 1];
        float a0 = fmaf(wx, rx0, fmaf(wy, ry, b));
        float a1 = fmaf(wx, rx1, fmaf(wy, ry, b));
        float a2 = fmaf(wx, rx2, fmaf(wy, ry, b));
        float a3 = fmaf(wx, rx3, fmaf(wy, ry, b));
        #pragma unroll
        for (int i = 0; i < CIN; ++i) {
            const float w = sW[o * 10 + 2 + i];
            a0 = fmaf(w, f[i].x, a0); a1 = fmaf(w, f[i].y, a1);
            a2 = fmaf(w, f[i].z, a2); a3 = fmaf(w, f[i].w, a3);
        }
        h0[o][0] = fmaxf(a0, 0.0f); h0[o][1] = fmaxf(a1, 0.0f);
        h0[o][2] = fmaxf(a2, 0.0f); h0[o][3] = fmaxf(a3, 0.0f);
    }

    float h1[CH][4];
    #pragma unroll
    for (int o = 0; o < CH; ++o) {
        const float b = sW[160 + o];
        float a0 = b, a1 = b, a2 = b, a3 = b;
        #pragma unroll
        for (int i = 0; i < CH; ++i) {
            const float w = sW[80 + o * CH + i];
            a0 = fmaf(w, h0[i][0], a0); a1 = fmaf(w, h0[i][1], a1);
            a2 = fmaf(w, h0[i][2], a2); a3 = fmaf(w, h0[i][3], a3);
        }
        h1[o][0] = fmaxf(a0, 0.0f); h1[o][1] = fmaxf(a1, 0.0f);
        h1[o][2] = fmaxf(a2, 0.0f); h1[o][3] = fmaxf(a3, 0.0f);
    }

    const float b2 = NEG_LOG2E * sW[168];
    float t0 = b2, t1 = b2, t2 = b2, t3 = b2;
    #pragma unroll
    for (int i = 0; i < CH; ++i) {
        const float w = NEG_LOG2E * sW[144 + i];
        t0 = fmaf(w, h1[i][0], t0); t1 = fmaf(w, h1[i][1], t1);
        t2 = fmaf(w, h1[i][2], t2); t3 = fmaf(w, h1[i][3], t3);
    }
    return make_float4(t0, t1, t2, t3);
}

__device__ __forceinline__ void upsample16(
    const float (*T)[W_IN], float* __restrict__ O,
    int r0, int rpl, int t)
{
    const int cm = 4 * t;
    const int cl = max(cm - 1, 0);

    const float4 mR = *(const float4*)&T[rpl + 1][cm];
    const float4 mQ = *(const float4*)&T[rpl][cm];
    const float  AR = T[rpl + 1][cl];       // == mR.x when t==0
    const float  AQ = T[rpl][cl];

    const float Aa = 0.5f * (AR + AQ);
    const float Ba = 0.5f * (mR.x + mQ.x);
    const float Ca = 0.5f * (mR.y + mQ.y);
    const float Da = 0.5f * (mR.z + mQ.z);
    const float Ea = 0.5f * (mR.w + mQ.w);

    float4 s0, s1, s2, s3;
    s0.x = __builtin_amdgcn_rcpf(1.0f + __builtin_amdgcn_exp2f(0.5f * (Aa + Ba)));
    s0.y = __builtin_amdgcn_rcpf(1.0f + __builtin_amdgcn_exp2f(Ba));
    s0.z = __builtin_amdgcn_rcpf(1.0f + __builtin_amdgcn_exp2f(0.5f * (Ba + Ca)));
    s0.w = __builtin_amdgcn_rcpf(1.0f + __builtin_amdgcn_exp2f(Ca));
    s1.x = __builtin_amdgcn_rcpf(1.0f + __builtin_amdgcn_exp2f(0.5f * (Ca + Da)));
    s1.y = __builtin_amdgcn_rcpf(1.0f + __builtin_amdgcn_exp2f(Da));
    s1.z = __builtin_amdgcn_rcpf(1.0f + __builtin_amdgcn_exp2f(0.5f * (Da + Ea)));
    s1.w = __builtin_amdgcn_rcpf(1.0f + __builtin_amdgcn_exp2f(Ea));

    s2.x = __builtin_amdgcn_rcpf(1.0f + __builtin_amdgcn_exp2f(0.5f * (AR + mR.x)));
    s2.y = __builtin_amdgcn_rcpf(1.0f + __builtin_amdgcn_exp2f(mR.x));
    s2.z = __builtin_amdgcn_rcpf(1.0f + __builtin_amdgcn_exp2f(0.5f * (mR.x + mR.y)));
    s2.w = __builtin_amdgcn_rcpf(1.0f + __builtin_amdgcn_exp2f(mR.y));
    s3.x = __builtin_amdgcn_rcpf(1.0f + __builtin_amdgcn_exp2f(0.5f * (mR.y + mR.z)));
    s3.y = __builtin_amdgcn_rcpf(1.0f + __builtin_amdgcn_exp2f(mR.z));
    s3.z = __builtin_amdgcn_rcpf(1.0f + __builtin_amdgcn_exp2f(0.5f * (mR.z + mR.w)));
    s3.w = __builtin_amdgcn_rcpf(1.0f + __builtin_amdgcn_exp2f(mR.w));

    float* O0 = O + (size_t)(2 * (r0 + rpl)) * OW + 8 * t;
    *(float4*)(O0)          = s0;
    *(float4*)(O0 + 4)      = s1;
    *(float4*)(O0 + OW)     = s2;
    *(float4*)(O0 + OW + 4) = s3;
}

__global__ __launch_bounds__(256, 3) void mask_head_fused(
    const float* __restrict__ mask_feats,   // (N, 8, H, W)
    const float* __restrict__ params,       // (n_inst, 169)
    const float* __restrict__ locations,    // (n_inst, 2)
    const int*   __restrict__ im_inds,      // (n_inst,)
    const int*   __restrict__ fpn_levels,   // (n_inst,)
    const float* __restrict__ soi_tab,      // (5,)
    float* __restrict__ out)                // (n_inst, 272, 400)
{
    __shared__ float sW[NPARAM];
    __shared__ float T[LROWS][W_IN];        // t = -log2e * logit, rows r0-1..r0+7

    const int inst = blockIdx.y;
    const int r0   = blockIdx.x * RB;
    const int tid  = threadIdx.x;

    const float* P = params + inst * NPARAM;
    if (tid < NPARAM) sW[tid] = P[tid];

    const float loc_x   = locations[2 * inst];
    const float loc_y   = locations[2 * inst + 1];
    const float inv_soi = 1.0f / soi_tab[fpn_levels[inst]];
    const float* F = mask_feats + (size_t)im_inds[inst] * (CIN * HWP);
    float* O = out + (size_t)inst * (OH * OW);
    __syncthreads();

    // ---- P1a: T slots 0..4 (rows r0-1..r0+3), 250 units x 4 px ----
    if (tid < 5 * (W_IN / 4)) {
        const int k = tid / 50;
        const int c = (tid - k * 50) * 4;
        const int r = min(max(r0 - 1 + k, 0), H_IN - 1);
        *(float4*)&T[k][c] = mlp4(F, sW, loc_x, loc_y, inv_soi, r, c);
    }
    __syncthreads();

    // ---- P2a (out rows 2r0..2r0+7, reads T[0..4]) + P1b (writes T[5..8]) ----
    // Disjoint T rows -> same barrier epoch. Stores issue early & spread.
    if (tid < 4 * (W_IN / 4)) {
        const int rpl = tid / 50;               // 0..3
        const int t   = tid - rpl * 50;
        upsample16(T, O, r0, rpl, t);
    }
    if (tid < 4 * (W_IN / 4)) {
        const int k = 5 + tid / 50;             // 5..8
        const int c = (tid - (k - 5) * 50) * 4;
        const int r = min(r0 - 1 + k, H_IN - 1);
        *(float4*)&T[k][c] = mlp4(F, sW, loc_x, loc_y, inv_soi, r, c);
    }
    __syncthreads();

    // ---- P2b: out rows 2r0+8..2r0+15, reads T[4..8] ----
    if (tid < 4 * (W_IN / 4)) {
        const int rpl = 4 + tid / 50;           // 4..7
        const int t   = tid - (rpl - 4) * 50;
        upsample16(T, O, r0, rpl, t);
    }
}

extern "C" void kernel_launch(void* const* d_in, const int* in_sizes, int n_in,
                              void* d_out, int out_size, void* d_ws, size_t ws_size,
                              hipStream_t stream) {
    const float* mask_feats = (const float*)d_in[0];
    const float* params     = (const float*)d_in[1];
    const float* locations  = (const float*)d_in[2];
    const int*   im_inds    = (const int*)d_in[3];
    const int*   fpn_levels = (const int*)d_in[4];
    const float* soi_tab    = (const float*)d_in[5];

    const int n_inst = in_sizes[1] / NPARAM;   // 128
    dim3 grid(NSTRIP, n_inst);                 // (17, 128)
    mask_head_fused<<<grid, 256, 0, stream>>>(
        mask_feats, params, locations, im_inds, fpn_levels, soi_tab, (float*)d_out);
}

// Round 13
// 26.213 us; speedup vs baseline: 9.3561x; 1.1129x over previous
//
#include <hip/hip_runtime.h>
#include <math.h>

typedef __fp16 h2 __attribute__((ext_vector_type(2)));

#define H_IN   136
#define W_IN   200
#define HWP    (H_IN * W_IN)       // 27200
#define OH     272
#define OW     400
#define RB     8                   // low-res rows per strip (17 strips)
#define NSTRIP 17
#define LROWS  (RB + 1)            // +1 halo row above
#define CH     8
#define CIN    8
#define NPARAM 169
#define NEG_LOG2E (-1.4426950408889634f)

// Param layout per instance (169 floats):
//  [0..79] w0[8][10] | [80..143] w1[8][8] | [144..151] w2[8]
//  [152..159] b0[8]  | [160..167] b1[8]   | [168] b2

// R13 = R12 with the type fixed: __builtin_amdgcn_cvt_pkrtz returns
// __fp16 ext_vector(2), so h2 is typedef'd over __fp16.
// ONE lever vs R8 — phase 1 MLP in packed fp16 (v_pk_fma_f16: one inst
// = 2 px), weights pre-packed (dup half2, layer-2 pre-scaled by -log2e).
// Phase 2 byte-identical to R8. Launch bounds (256,3) = R8's proven cap.

__device__ __forceinline__ h2 pkrtz(float a, float b) {
    return __builtin_amdgcn_cvt_pkrtz(a, b);
}

__global__ __launch_bounds__(256, 3) void mask_head_fused(
    const float* __restrict__ mask_feats,   // (N, 8, H, W)
    const float* __restrict__ params,       // (n_inst, 169)
    const float* __restrict__ locations,    // (n_inst, 2)
    const int*   __restrict__ im_inds,      // (n_inst,)
    const int*   __restrict__ fpn_levels,   // (n_inst,)
    const float* __restrict__ soi_tab,      // (5,)
    float* __restrict__ out)                // (n_inst, 272, 400)
{
    __shared__ h2    sW[NPARAM];            // packed (dup) fp16 weights
    __shared__ float T[LROWS][W_IN];        // t = -log2e * logit

    const int inst = blockIdx.y;
    const int r0   = blockIdx.x * RB;
    const int tid  = threadIdx.x;

    const float* P = params + inst * NPARAM;
    if (tid < NPARAM) {
        float w = P[tid];
        if ((tid >= 144 && tid < 152) || tid == 168) w *= NEG_LOG2E;
        const __fp16 hw = (__fp16)w;
        h2 v; v.x = hw; v.y = hw;
        sW[tid] = v;
    }

    const float loc_x   = locations[2 * inst];
    const float loc_y   = locations[2 * inst + 1];
    const float inv_soi = 1.0f / soi_tab[fpn_levels[inst]];
    const float* F = mask_feats + (size_t)im_inds[inst] * (CIN * HWP);
    float* O = out + (size_t)inst * (OH * OW);
    __syncthreads();

    // ---- Phase 1: 225 units of 8 px (4 half2 slots), packed fp16 MLP ----
    if (tid < LROWS * (W_IN / 8)) {
        const int k = tid / 25;
        const int c = (tid - k * 25) * 8;
        const int r = min(max(r0 - 1 + k, 0), H_IN - 1);

        // features -> fp16 pairs
        h2 f[CIN][4];
        #pragma unroll
        for (int ch = 0; ch < CIN; ++ch) {
            const float* q = F + ch * HWP + r * W_IN + c;
            const float4 A = *(const float4*)q;
            const float4 B = *(const float4*)(q + 4);
            f[ch][0] = pkrtz(A.x, A.y); f[ch][1] = pkrtz(A.z, A.w);
            f[ch][2] = pkrtz(B.x, B.y); f[ch][3] = pkrtz(B.z, B.w);
        }

        // rel coords -> fp16 pairs
        const float ry  = (loc_y - (float)(r * 8 + 4)) * inv_soi;
        const float dx  = -8.0f * inv_soi;
        const float rx0 = (loc_x - (float)(c * 8 + 4)) * inv_soi;
        h2 rxh[4];
        #pragma unroll
        for (int s = 0; s < 4; ++s)
            rxh[s] = pkrtz(rx0 + (float)(2 * s) * dx, rx0 + (float)(2 * s + 1) * dx);
        const h2 ryh = pkrtz(ry, ry);
        const h2 z2  = {(__fp16)0.0f, (__fp16)0.0f};

        // layer 0: 10 -> 8, relu
        h2 h0[CH][4];
        #pragma unroll
        for (int o = 0; o < CH; ++o) {
            const h2 base = __builtin_elementwise_fma(sW[o * 10 + 1], ryh, sW[152 + o]);
            const h2 wx = sW[o * 10];
            h2 a[4];
            #pragma unroll
            for (int s = 0; s < 4; ++s) a[s] = __builtin_elementwise_fma(wx, rxh[s], base);
            #pragma unroll
            for (int i = 0; i < CIN; ++i) {
                const h2 w = sW[o * 10 + 2 + i];
                #pragma unroll
                for (int s = 0; s < 4; ++s) a[s] = __builtin_elementwise_fma(w, f[i][s], a[s]);
            }
            #pragma unroll
            for (int s = 0; s < 4; ++s) h0[o][s] = __builtin_elementwise_max(a[s], z2);
        }

        // layer 1: 8 -> 8, relu
        h2 h1[CH][4];
        #pragma unroll
        for (int o = 0; o < CH; ++o) {
            const h2 b = sW[160 + o];
            h2 a[4] = {b, b, b, b};
            #pragma unroll
            for (int i = 0; i < CH; ++i) {
                const h2 w = sW[80 + o * CH + i];
                #pragma unroll
                for (int s = 0; s < 4; ++s) a[s] = __builtin_elementwise_fma(w, h0[i][s], a[s]);
            }
            #pragma unroll
            for (int s = 0; s < 4; ++s) h1[o][s] = __builtin_elementwise_max(a[s], z2);
        }

        // layer 2: 8 -> 1 (weights pre-scaled by -log2e at staging)
        const h2 b2 = sW[168];
        h2 t[4] = {b2, b2, b2, b2};
        #pragma unroll
        for (int i = 0; i < CH; ++i) {
            const h2 w = sW[144 + i];
            #pragma unroll
            for (int s = 0; s < 4; ++s) t[s] = __builtin_elementwise_fma(w, h1[i][s], t[s]);
        }

        *(float4*)&T[k][c] = make_float4((float)t[0].x, (float)t[0].y,
                                         (float)t[1].x, (float)t[1].y);
        *(float4*)&T[k][c + 4] = make_float4((float)t[2].x, (float)t[2].y,
                                             (float)t[3].x, (float)t[3].y);
    }
    __syncthreads();

    // ---- Phase 2: 400 units of 16 px (8 wide x 2 output rows) — as R8 ----
    #pragma unroll
    for (int it = 0; it < 2; ++it) {
        const int s = tid + 256 * it;
        if (s < RB * (W_IN / 4)) {
            const int rpl = s / (W_IN / 4);         // 0..7
            const int t   = s - rpl * (W_IN / 4);   // 0..49
            const int cm  = 4 * t;
            const int cl  = max(cm - 1, 0);

            const float4 mR = *(const float4*)&T[rpl + 1][cm];
            const float4 mQ = *(const float4*)&T[rpl][cm];
            const float  AR = T[rpl + 1][cl];       // == mR.x when t==0
            const float  AQ = T[rpl][cl];

            const float Aa = 0.5f * (AR + AQ);
            const float Ba = 0.5f * (mR.x + mQ.x);
            const float Ca = 0.5f * (mR.y + mQ.y);
            const float Da = 0.5f * (mR.z + mQ.z);
            const float Ea = 0.5f * (mR.w + mQ.w);

            float4 s0, s1, s2, s3;
            s0.x = __builtin_amdgcn_rcpf(1.0f + __builtin_amdgcn_exp2f(0.5f * (Aa + Ba)));
            s0.y = __builtin_amdgcn_rcpf(1.0f + __builtin_amdgcn_exp2f(Ba));
            s0.z = __builtin_amdgcn_rcpf(1.0f + __builtin_amdgcn_exp2f(0.5f * (Ba + Ca)));
            s0.w = __builtin_amdgcn_rcpf(1.0f + __builtin_amdgcn_exp2f(Ca));
            s1.x = __builtin_amdgcn_rcpf(1.0f + __builtin_amdgcn_exp2f(0.5f * (Ca + Da)));
            s1.y = __builtin_amdgcn_rcpf(1.0f + __builtin_amdgcn_exp2f(Da));
            s1.z = __builtin_amdgcn_rcpf(1.0f + __builtin_amdgcn_exp2f(0.5f * (Da + Ea)));
            s1.w = __builtin_amdgcn_rcpf(1.0f + __builtin_amdgcn_exp2f(Ea));

            s2.x = __builtin_amdgcn_rcpf(1.0f + __builtin_amdgcn_exp2f(0.5f * (AR + mR.x)));
            s2.y = __builtin_amdgcn_rcpf(1.0f + __builtin_amdgcn_exp2f(mR.x));
            s2.z = __builtin_amdgcn_rcpf(1.0f + __builtin_amdgcn_exp2f(0.5f * (mR.x + mR.y)));
            s2.w = __builtin_amdgcn_rcpf(1.0f + __builtin_amdgcn_exp2f(mR.y));
            s3.x = __builtin_amdgcn_rcpf(1.0f + __builtin_amdgcn_exp2f(0.5f * (mR.y + mR.z)));
            s3.y = __builtin_amdgcn_rcpf(1.0f + __builtin_amdgcn_exp2f(mR.z));
            s3.z = __builtin_amdgcn_rcpf(1.0f + __builtin_amdgcn_exp2f(0.5f * (mR.z + mR.w)));
            s3.w = __builtin_amdgcn_rcpf(1.0f + __builtin_amdgcn_exp2f(mR.w));

            float* O0 = O + (size_t)(2 * (r0 + rpl)) * OW + 8 * t;
            *(float4*)(O0)          = s0;
            *(float4*)(O0 + 4)      = s1;
            *(float4*)(O0 + OW)     = s2;
            *(float4*)(O0 + OW + 4) = s3;
        }
    }
}

extern "C" void kernel_launch(void* const* d_in, const int* in_sizes, int n_in,
                              void* d_out, int out_size, void* d_ws, size_t ws_size,
                              hipStream_t stream) {
    const float* mask_feats = (const float*)d_in[0];
    const float* params     = (const float*)d_in[1];
    const float* locations  = (const float*)d_in[2];
    const int*   im_inds    = (const int*)d_in[3];
    const int*   fpn_levels = (const int*)d_in[4];
    const float* soi_tab    = (const float*)d_in[5];

    const int n_inst = in_sizes[1] / NPARAM;   // 128
    dim3 grid(NSTRIP, n_inst);                 // (17, 128)
    mask_head_fused<<<grid, 256, 0, stream>>>(
        mask_feats, params, locations, im_inds, fpn_levels, soi_tab, (float*)d_out);
}